// Round 8
// baseline (516.068 us; speedup 1.0000x reference)
//
#include <hip/hip_runtime.h>
#include <math.h>

// CapsuleLayer dynamic routing — round 15: in-kernel deputy reduce (6 -> 3
// dispatches). B=64, N=4096, I=8, C=32, D=16, 3 routing iterations.
//
// Round-14 post-mortem: pass12 restructure bought ~1.6us/kernel -> barrier
// chain wasn't dominant. Budget: work sum ~115-120us vs 167.6 wall -> ~50us
// is 5 serial dispatch boundaries (~8-10us each). Round 15 folds each
// reduce_squash into the tail of its pass kernel via a ticket counter:
//   - each block: threadfence -> syncthreads -> t0 agent-scope fetch_add
//     (ticket). Last 128 tickets become reducer blocks (they just ran ->
//     resident; deadlock-proof without co-residency assumptions).
//   - reducer t0 spin-loads counter (acquire + s_sleep) until all arrived,
//     then block reduces slice = ticket-(NBLOCKS-128) (verbatim squash).
//   - counters zeroed by capture-safe hipMemsetAsync; Ocum visibility to
//     the next dispatch via normal kernel boundary.
// Pass bodies verbatim round 14 (pass0: cj-split + LDS-staged x + Wh/xh
// emit; pass12: 2 n-steps/barrier, fp16 acc).
//
// ws (NPB=16): Wh 32 MiB | partial 16 MiB | xh 4 MiB | Ocum 64 KiB |
//              ctr 12 B  (52.07 MiB)

typedef __fp16 h2 __attribute__((ext_vector_type(2)));
typedef __fp16 half4 __attribute__((ext_vector_type(4)));
typedef float f32x16 __attribute__((ext_vector_type(16)));

union U2 { h2 h; unsigned u; };

__device__ __forceinline__ float fdot2(h2 a, h2 b, float c) {
    return __builtin_amdgcn_fdot2(a, b, c, false);
}
__device__ __forceinline__ h2 uash2(unsigned u) { U2 t; t.u = u; return t.h; }

// ---- reduce + squash + Ocum update body (slice = 0..127, 512 thr) ---------
template <int NB>
__device__ __forceinline__ void reduce_body(const unsigned* __restrict__ partial32,
                                            ushort* __restrict__ OcumG,
                                            float* __restrict__ out,
                                            int passIdx, int slice, int t) {
    const int gtid = slice * 512 + t;                 // 0..65535
    const int oid = gtid >> 2, sub = gtid & 3;
    const int b = oid >> 8, cjp = oid & 255;
    const int bt = b >> 5, bl = b & 31;
    const unsigned base = (unsigned)bt * (unsigned)NB * 8192u + (unsigned)bl * 256u + (unsigned)cjp;
    float sx = 0.f, sy = 0.f;
    #pragma unroll 8
    for (int i = 0; i < NB / 4; ++i) {
        U2 v; v.u = partial32[base + (unsigned)(sub + 4 * i) * 8192u];
        sx += (float)v.h.x;
        sy += (float)v.h.y;
    }
    sx += __shfl_xor(sx, 1, 64); sy += __shfl_xor(sy, 1, 64);
    sx += __shfl_xor(sx, 2, 64); sy += __shfl_xor(sy, 2, 64);
    float s2 = sx * sx + sy * sy;                     // sum over capsule's 8 cjp
    s2 += __shfl_xor(s2, 4, 64);
    s2 += __shfl_xor(s2, 8, 64);
    s2 += __shfl_xor(s2, 16, 64);
    float scale = (s2 / (1.f + s2)) / sqrtf(s2 + 1e-7f);
    float o0 = scale * sx, o1 = scale * sy;

    if (sub == 0) {
        unsigned* ocp = reinterpret_cast<unsigned*>(OcumG) + b * 256 + cjp;
        float a0 = o0, a1 = o1;
        if (passIdx) {
            U2 old; old.u = *ocp;
            a0 += (float)old.h.x;
            a1 += (float)old.h.y;
        }
        U2 nw; nw.h = __builtin_amdgcn_cvt_pkrtz(a0, a1);
        *ocp = nw.u;
        if (passIdx == 2) {
            out[b * 512 + cjp * 2] = o0;
            out[b * 512 + cjp * 2 + 1] = o1;
        }
    }
}

// ---- fused pass kernel: pass body + arrival + deputy reduce ---------------

template <int PASS, int NPB>
__global__ __launch_bounds__(512, 4) void fused(
    const float* __restrict__ W,      // [C][N][D][I] f32
    const float* __restrict__ x,      // [B][N][I] f32
    ushort* __restrict__ Wh,          // [N][CJ][I] fp16
    ushort* __restrict__ xh,          // [N][B][I] fp16
    ushort* __restrict__ OcumG,       // [B][CJ] fp16
    unsigned* __restrict__ partial,   // [bt*NB+nblk][bl 32][cjp 256] u32(h2)
    float* __restrict__ out,
    unsigned* __restrict__ ctr)
{
    constexpr int NB = 4096 / NPB;
    constexpr int NBLOCKS = 2 * NB;
    const int bid = blockIdx.x;
    const int t = threadIdx.x, l = t & 63, w = t >> 6;
    const int bl = l & 31, hi = l >> 5;

    __shared__ unsigned sep[8192];                   // 32KB epilogue staging
    __shared__ unsigned s_ticket;

    if constexpr (PASS == 0) {
        // ================= pass 0: uniform coupling, cj-split ==============
        const int half = bid / NB, nblk = bid % NB;
        const int n0 = nblk * NPB;
        const int cj = half * 256 + w * 32 + bl;

        __shared__ __align__(16) ushort xs[NPB * 512];  // [n][b][i] swizzled

        #pragma unroll
        for (int rep = 0; rep < NPB / 4; ++rep) {
            const int idx = t + rep * 512;
            const int b = idx / (2 * NPB), f4 = idx % (2 * NPB);
            const int nl = f4 >> 1, isl = f4 & 1;
            float4 v = *reinterpret_cast<const float4*>(
                x + (size_t)b * 32768 + (size_t)n0 * 8 + f4 * 4);
            half4 h;
            h[0] = (__fp16)v.x; h[1] = (__fp16)v.y; h[2] = (__fp16)v.z; h[3] = (__fp16)v.w;
            const int slot = (nl * 128 + b * 2 + isl) ^ ((nl & 7) << 1) ^ ((b >> 3) & 3);
            *reinterpret_cast<half4*>(xs + slot * 4) = h;
        }
        __syncthreads();

        if (half == 0) {
            #pragma unroll
            for (int rep = 0; rep < NPB / 4; ++rep) {
                const int u = t + rep * 512;
                const int nl = u >> 7, b = (u >> 1) & 63, isl = u & 1;
                const int slot = (nl * 128 + b * 2 + isl) ^ ((nl & 7) << 1) ^ ((b >> 3) & 3);
                half4 h = *reinterpret_cast<const half4*>(xs + slot * 4);
                *reinterpret_cast<half4*>(xh + (size_t)n0 * 512 + u * 4) = h;
            }
        }

        const float* wb = W + (size_t)(cj >> 4) * 524288 + (size_t)n0 * 128 + (cj & 15) * 8 + hi * 4;
        ushort* whp = Wh + ((size_t)n0 * 512 + cj) * 8 + hi * 4;

        f32x16 acc0 = {}, acc1 = {};                 // b 0-31 / b 32-63
        float4 wv = *reinterpret_cast<const float4*>(wb);
        #pragma unroll 1
        for (int s = 0; s < NPB; ++s) {
            float4 wvn;
            if (s < NPB - 1)
                wvn = *reinterpret_cast<const float4*>(wb + (s + 1) * 128);
            const int sw = ((s & 7) << 1) ^ ((bl >> 3) & 3);
            const int slot0 = (s * 128 + bl * 2 + hi) ^ sw;
            const int slot1 = (s * 128 + bl * 2 + 64 + hi) ^ sw;
            half4 b0 = *reinterpret_cast<const half4*>(xs + slot0 * 4);
            half4 b1 = *reinterpret_cast<const half4*>(xs + slot1 * 4);
            half4 a;
            a[0] = (__fp16)wv.x; a[1] = (__fp16)wv.y; a[2] = (__fp16)wv.z; a[3] = (__fp16)wv.w;
            *reinterpret_cast<half4*>(whp + (size_t)s * 4096) = a;
            acc0 = __builtin_amdgcn_mfma_f32_32x32x8f16(a, b0, acc0, 0, 0, 0);
            acc1 = __builtin_amdgcn_mfma_f32_32x32x8f16(a, b1, acc1, 0, 0, 0);
            wv = wvn;
        }
        #pragma unroll
        for (int r = 0; r < 16; ++r) { acc0[r] *= 0.03125f; acc1[r] *= 0.03125f; }

        // epilogue: sep[b 64][cjp_local 128], XOR-swizzled by b
        #pragma unroll
        for (int hb = 0; hb < 2; ++hb) {
            #pragma unroll
            for (int q = 0; q < 8; ++q) {
                const float e0 = hb ? acc1[2 * q] : acc0[2 * q];
                const float e1 = hb ? acc1[2 * q + 1] : acc0[2 * q + 1];
                U2 u; u.h = __builtin_amdgcn_cvt_pkrtz(e0, e1);
                const int cjp = w * 16 + 4 * (q >> 1) + (q & 1) + 2 * hi;
                const int bb = bl + 32 * hb;
                sep[bb * 128 + (cjp ^ bb)] = u.u;
            }
        }
        __syncthreads();
        #pragma unroll
        for (int u2 = 0; u2 < 16; ++u2) {
            const int idx = t + u2 * 512;
            const int ub = idx >> 7, ucjp = idx & 127;
            partial[(size_t)((ub >> 5) * NB + nblk) * 8192 + (ub & 31) * 256 + half * 128 + ucjp]
                = sep[ub * 128 + (ucjp ^ ub)];
        }
    } else {
        // ================= pass 1/2: softmax coupling, b-split =============
        const int bt = bid / NB, nblk = bid % NB;
        const int n0 = nblk * NPB;
        const int b = bt * 32 + bl;

        __shared__ __align__(16) float pd[2][2][32][12];

        const int cj0 = w * 64 + bl, cj1 = cj0 + 32;
        const ushort* xb = xh + ((size_t)n0 * 64 + b) * 8 + hi * 4;
        const ushort* whp0 = Wh + ((size_t)n0 * 512 + cj0) * 8 + hi * 4;
        const ushort* whp1 = Wh + ((size_t)n0 * 512 + cj1) * 8 + hi * 4;

        h2 oc[2][8];
        {
            const unsigned* og = reinterpret_cast<const unsigned*>(OcumG);
            #pragma unroll
            for (int mt = 0; mt < 2; ++mt) {
                const int cA = 4 * w + 2 * mt;
                const unsigned idx = (unsigned)b * 256 + cA * 8 + hi * 2;
                oc[mt][0] = uash2(og[idx]);      oc[mt][1] = uash2(og[idx + 1]);
                oc[mt][2] = uash2(og[idx + 4]);  oc[mt][3] = uash2(og[idx + 5]);
                oc[mt][4] = uash2(og[idx + 8]);  oc[mt][5] = uash2(og[idx + 9]);
                oc[mt][6] = uash2(og[idx + 12]); oc[mt][7] = uash2(og[idx + 13]);
            }
        }

        f32x16 zero = {};
        h2 acc0h[8], acc1h[8];
        #pragma unroll
        for (int q = 0; q < 8; ++q) {
            acc0h[q] = (h2)(__fp16)0.f;
            acc1h[q] = (h2)(__fp16)0.f;
        }

        half4 a0A = *reinterpret_cast<const half4*>(whp0);
        half4 a1A = *reinterpret_cast<const half4*>(whp1);
        half4 bfA = *reinterpret_cast<const half4*>(xb);
        half4 a0B = *reinterpret_cast<const half4*>(whp0 + 4096);
        half4 a1B = *reinterpret_cast<const half4*>(whp1 + 4096);
        half4 bfB = *reinterpret_cast<const half4*>(xb + 512);

        #pragma unroll 1
        for (int p = 0; p < NPB / 2; ++p) {
            half4 a0An, a1An, bfAn, a0Bn, a1Bn, bfBn;
            if (p < NPB / 2 - 1) {
                const int sA = 2 * p + 2, sB = 2 * p + 3;
                a0An = *reinterpret_cast<const half4*>(whp0 + (size_t)sA * 4096);
                a1An = *reinterpret_cast<const half4*>(whp1 + (size_t)sA * 4096);
                bfAn = *reinterpret_cast<const half4*>(xb + (size_t)sA * 512);
                a0Bn = *reinterpret_cast<const half4*>(whp0 + (size_t)sB * 4096);
                a1Bn = *reinterpret_cast<const half4*>(whp1 + (size_t)sB * 4096);
                bfBn = *reinterpret_cast<const half4*>(xb + (size_t)sB * 512);
            }
            h2 hA0[8], hA1[8];
            {
                f32x16 d0 = __builtin_amdgcn_mfma_f32_32x32x8f16(a0A, bfA, zero, 0, 0, 0);
                f32x16 d1 = __builtin_amdgcn_mfma_f32_32x32x8f16(a1A, bfA, zero, 0, 0, 0);
                #pragma unroll
                for (int q = 0; q < 8; ++q) {
                    hA0[q] = __builtin_amdgcn_cvt_pkrtz(d0[2 * q], d0[2 * q + 1]);
                    hA1[q] = __builtin_amdgcn_cvt_pkrtz(d1[2 * q], d1[2 * q + 1]);
                }
            }
            float pA0_A = fdot2(hA0[3], oc[0][3], fdot2(hA0[2], oc[0][2], fdot2(hA0[1], oc[0][1], fdot2(hA0[0], oc[0][0], 0.f))));
            float pB0_A = fdot2(hA0[7], oc[0][7], fdot2(hA0[6], oc[0][6], fdot2(hA0[5], oc[0][5], fdot2(hA0[4], oc[0][4], 0.f))));
            float pA1_A = fdot2(hA1[3], oc[1][3], fdot2(hA1[2], oc[1][2], fdot2(hA1[1], oc[1][1], fdot2(hA1[0], oc[1][0], 0.f))));
            float pB1_A = fdot2(hA1[7], oc[1][7], fdot2(hA1[6], oc[1][6], fdot2(hA1[5], oc[1][5], fdot2(hA1[4], oc[1][4], 0.f))));
            h2 hB0[8], hB1[8];
            {
                f32x16 d0 = __builtin_amdgcn_mfma_f32_32x32x8f16(a0B, bfB, zero, 0, 0, 0);
                f32x16 d1 = __builtin_amdgcn_mfma_f32_32x32x8f16(a1B, bfB, zero, 0, 0, 0);
                #pragma unroll
                for (int q = 0; q < 8; ++q) {
                    hB0[q] = __builtin_amdgcn_cvt_pkrtz(d0[2 * q], d0[2 * q + 1]);
                    hB1[q] = __builtin_amdgcn_cvt_pkrtz(d1[2 * q], d1[2 * q + 1]);
                }
            }
            float pA0_B = fdot2(hB0[3], oc[0][3], fdot2(hB0[2], oc[0][2], fdot2(hB0[1], oc[0][1], fdot2(hB0[0], oc[0][0], 0.f))));
            float pB0_B = fdot2(hB0[7], oc[0][7], fdot2(hB0[6], oc[0][6], fdot2(hB0[5], oc[0][5], fdot2(hB0[4], oc[0][4], 0.f))));
            float pA1_B = fdot2(hB1[3], oc[1][3], fdot2(hB1[2], oc[1][2], fdot2(hB1[1], oc[1][1], fdot2(hB1[0], oc[1][0], 0.f))));
            float pB1_B = fdot2(hB1[7], oc[1][7], fdot2(hB1[6], oc[1][6], fdot2(hB1[5], oc[1][5], fdot2(hB1[4], oc[1][4], 0.f))));

            pA0_A += __shfl_xor(pA0_A, 32, 64);
            pB0_A += __shfl_xor(pB0_A, 32, 64);
            pA1_A += __shfl_xor(pA1_A, 32, 64);
            pB1_A += __shfl_xor(pB1_A, 32, 64);
            pA0_B += __shfl_xor(pA0_B, 32, 64);
            pB0_B += __shfl_xor(pB0_B, 32, 64);
            pA1_B += __shfl_xor(pA1_B, 32, 64);
            pB1_B += __shfl_xor(pB1_B, 32, 64);

            float eA0_A = __expf(pA0_A), eB0_A = __expf(pB0_A);
            float eA1_A = __expf(pA1_A), eB1_A = __expf(pB1_A);
            float eA0_B = __expf(pA0_B), eB0_B = __expf(pB0_B);
            float eA1_B = __expf(pA1_B), eB1_B = __expf(pB1_B);

            const int buf = p & 1;
            if (l < 32) {
                pd[buf][0][bl][w] = eA0_A + eB0_A + eA1_A + eB1_A;
                pd[buf][1][bl][w] = eA0_B + eB0_B + eA1_B + eB1_B;
            }
            __syncthreads();
            const float4 qa0 = *reinterpret_cast<const float4*>(&pd[buf][0][bl][0]);
            const float4 qa1 = *reinterpret_cast<const float4*>(&pd[buf][0][bl][4]);
            const float4 qb0 = *reinterpret_cast<const float4*>(&pd[buf][1][bl][0]);
            const float4 qb1 = *reinterpret_cast<const float4*>(&pd[buf][1][bl][4]);
            const float rdA = __builtin_amdgcn_rcpf(qa0.x + qa0.y + qa0.z + qa0.w +
                                                    qa1.x + qa1.y + qa1.z + qa1.w);
            const float rdB = __builtin_amdgcn_rcpf(qb0.x + qb0.y + qb0.z + qb0.w +
                                                    qb1.x + qb1.y + qb1.z + qb1.w);

            h2 c0A, c1A, c0B, c1B, c2A, c3A, c2B, c3B;
            c0A.x = (__fp16)(eA0_A * rdA); c0A.y = c0A.x;
            c1A.x = (__fp16)(eB0_A * rdA); c1A.y = c1A.x;
            c2A.x = (__fp16)(eA1_A * rdA); c2A.y = c2A.x;
            c3A.x = (__fp16)(eB1_A * rdA); c3A.y = c3A.x;
            c0B.x = (__fp16)(eA0_B * rdB); c0B.y = c0B.x;
            c1B.x = (__fp16)(eB0_B * rdB); c1B.y = c1B.x;
            c2B.x = (__fp16)(eA1_B * rdB); c2B.y = c2B.x;
            c3B.x = (__fp16)(eB1_B * rdB); c3B.y = c3B.x;

            #pragma unroll
            for (int q = 0; q < 4; ++q) {
                acc0h[q] = hA0[q] * c0A + acc0h[q];
                acc0h[q + 4] = hA0[q + 4] * c1A + acc0h[q + 4];
                acc1h[q] = hA1[q] * c2A + acc1h[q];
                acc1h[q + 4] = hA1[q + 4] * c3A + acc1h[q + 4];
            }
            #pragma unroll
            for (int q = 0; q < 4; ++q) {
                acc0h[q] = hB0[q] * c0B + acc0h[q];
                acc0h[q + 4] = hB0[q + 4] * c1B + acc0h[q + 4];
                acc1h[q] = hB1[q] * c2B + acc1h[q];
                acc1h[q + 4] = hB1[q + 4] * c3B + acc1h[q + 4];
            }
            a0A = a0An; a1A = a1An; bfA = bfAn;
            a0B = a0Bn; a1B = a1Bn; bfB = bfBn;
        }

        __syncthreads();
        #pragma unroll
        for (int mt = 0; mt < 2; ++mt) {
            #pragma unroll
            for (int q = 0; q < 8; ++q) {
                U2 u; u.h = mt ? acc1h[q] : acc0h[q];
                const int cjp = w * 32 + mt * 16 + 4 * (q >> 1) + (q & 1) + 2 * hi;
                sep[bl * 256 + (cjp ^ bl)] = u.u;
            }
        }
        __syncthreads();
        const unsigned gbase = (unsigned)bid * 8192;
        #pragma unroll
        for (int u2 = 0; u2 < 16; ++u2) {
            const int idx = t + u2 * 512;
            const int ubl = idx >> 8, ucjp = idx & 255;
            partial[gbase + idx] = sep[ubl * 256 + (ucjp ^ ubl)];
        }
    }

    // ---- arrival + deputy reduce ------------------------------------------
    __threadfence();                                 // release partial stores
    __syncthreads();
    if (t == 0)
        s_ticket = __hip_atomic_fetch_add(ctr, 1u, __ATOMIC_ACQ_REL,
                                          __HIP_MEMORY_SCOPE_AGENT);
    __syncthreads();
    const unsigned ticket = s_ticket;
    if (ticket >= (unsigned)(NBLOCKS - 128)) {
        if (t == 0) {
            while (__hip_atomic_load(ctr, __ATOMIC_ACQUIRE,
                                     __HIP_MEMORY_SCOPE_AGENT) < (unsigned)NBLOCKS)
                __builtin_amdgcn_s_sleep(2);
        }
        __syncthreads();
        reduce_body<NB>(partial, OcumG, out, PASS,
                        (int)(ticket - (unsigned)(NBLOCKS - 128)), t);
    }
}

// ---- host ------------------------------------------------------------------

extern "C" void kernel_launch(void* const* d_in, const int* in_sizes, int n_in,
                              void* d_out, int out_size, void* d_ws, size_t ws_size,
                              hipStream_t stream) {
    const float* x = (const float*)d_in[0];
    const float* W = (const float*)d_in[1];
    float* out = (float*)d_out;

    char* ws = (char*)d_ws;
    ushort* Wh = (ushort*)ws;                                        // 32 MiB
    const size_t MiB = 1024 * 1024;

    if (ws_size >= 52 * MiB + 65536 + 16) {
        // NPB=16: partial 16 MiB | xh 4 MiB | Ocum 64 KiB | ctr 12 B
        unsigned* partialU = (unsigned*)(ws + 32 * MiB);
        ushort* xh = (ushort*)(ws + 48 * MiB);
        ushort* OcumG = (ushort*)(ws + 52 * MiB);
        unsigned* ctrs = (unsigned*)(ws + 52 * MiB + 65536);
        hipMemsetAsync(ctrs, 0, 16, stream);
        fused<0, 16><<<512, 512, 0, stream>>>(W, x, Wh, xh, OcumG, partialU, out, ctrs + 0);
        fused<1, 16><<<512, 512, 0, stream>>>(W, x, Wh, xh, OcumG, partialU, out, ctrs + 1);
        fused<2, 16><<<512, 512, 0, stream>>>(W, x, Wh, xh, OcumG, partialU, out, ctrs + 2);
    } else {
        // fallback NPB=32: partial 8 MiB | xh 4 MiB | Ocum 64 KiB | ctr
        unsigned* partialU = (unsigned*)(ws + 32 * MiB);
        ushort* xh = (ushort*)(ws + 40 * MiB);
        ushort* OcumG = (ushort*)(ws + 44 * MiB);
        unsigned* ctrs = (unsigned*)(ws + 44 * MiB + 65536);
        hipMemsetAsync(ctrs, 0, 16, stream);
        fused<0, 32><<<256, 512, 0, stream>>>(W, x, Wh, xh, OcumG, partialU, out, ctrs + 0);
        fused<1, 32><<<256, 512, 0, stream>>>(W, x, Wh, xh, OcumG, partialU, out, ctrs + 1);
        fused<2, 32><<<256, 512, 0, stream>>>(W, x, Wh, xh, OcumG, partialU, out, ctrs + 2);
    }
}

// Round 9
// 350.740 us; speedup vs baseline: 1.4714x; 1.4714x over previous
//
#include <hip/hip_runtime.h>
#include <math.h>

// CapsuleLayer dynamic routing — round 16: 4 blocks/CU via LDS union + NPB=8.
// B=64, N=4096, I=8, C=32, D=16, 3 routing iterations.
//
// Round-15 post-mortem: deputy-reduce ticket sync cost ~120us/kernel tail
// (agent-scope spin across non-coherent XCD L2s) -> 516us. Third strike for
// device-side cross-block sync on MI355X (round 9 grid.sync ~40us/sync).
// Reverted to the 6-dispatch round-14 structure permanently.
// Round 16: all kernels are latency-bound (<10% on every pipe); raise
// resident blocks 2 -> 4 per CU:
//  - LDS union: sep (32KB, epilogue-only) overlaps xs/pd (loop-only) in ONE
//    32KB buffer (extra barrier in pass0 protects the overlap) -> 48->32KB.
//  - launch_bounds(512,8): VGPR cap 64 (bodies measured 36-40 -> no spill).
//  - NPB 16->8: grid 1024 = 4 blocks/CU all-resident; partial 32 MiB;
//    reduce 8 threads/output (shfl 1,2,4 combine; s2 over 8,16,32).
// Math verbatim round 14 (MFMA map, swizzles, fp16 acc, squash).
//
// ws (NPB=8): Wh 32 MiB | partial 32 MiB | xh 4 MiB | Ocum 64 KiB (68.07)

typedef __fp16 h2 __attribute__((ext_vector_type(2)));
typedef __fp16 half4 __attribute__((ext_vector_type(4)));
typedef float f32x16 __attribute__((ext_vector_type(16)));

union U2 { h2 h; unsigned u; };

__device__ __forceinline__ float fdot2(h2 a, h2 b, float c) {
    return __builtin_amdgcn_fdot2(a, b, c, false);
}
__device__ __forceinline__ h2 uash2(unsigned u) { U2 t; t.u = u; return t.h; }

// ---- pass 0: uniform coupling; cj-split; LDS-staged x; emits Wh and xh ----

template <int NPB>
__global__ __launch_bounds__(512, 8) void pass0_kernel(
    const float* __restrict__ W,      // [C][N][D][I] f32
    const float* __restrict__ x,      // [B][N][I] f32
    ushort* __restrict__ Wh,          // [N][CJ][I] fp16
    ushort* __restrict__ xh,          // [N][B][I] fp16
    unsigned* __restrict__ partial)   // [(bt*NB+nblk)][bl 32][cjp 256] u32(h2)
{
    constexpr int NB = 4096 / NPB;
    const int bid = blockIdx.x;
    const int half = bid / NB, nblk = bid % NB;      // XCD = bid%8 = nblk%8
    const int n0 = nblk * NPB;
    const int t = threadIdx.x, l = t & 63, w = t >> 6;
    const int bl = l & 31, hi = l >> 5;
    const int cj = half * 256 + w * 32 + bl;         // this lane's A-row

    // LDS union: xs (loop phase) and sep (epilogue phase) share 32KB.
    __shared__ __align__(16) unsigned shbuf[8192];
    ushort* xs = reinterpret_cast<ushort*>(shbuf);   // [n][b][i] fp16 swizzled
    unsigned* sep = shbuf;                           // epilogue staging

    // ---- stage x tile: coalesced f32 read -> fp16 -> swizzled LDS --------
    #pragma unroll
    for (int rep = 0; rep < NPB / 4; ++rep) {
        const int idx = t + rep * 512;               // float4 id, 0..NPB*128-1
        const int b = idx / (2 * NPB), f4 = idx % (2 * NPB);
        const int nl = f4 >> 1, isl = f4 & 1;
        float4 v = *reinterpret_cast<const float4*>(
            x + (size_t)b * 32768 + (size_t)n0 * 8 + f4 * 4);
        half4 h;
        h[0] = (__fp16)v.x; h[1] = (__fp16)v.y; h[2] = (__fp16)v.z; h[3] = (__fp16)v.w;
        const int slot = (nl * 128 + b * 2 + isl) ^ ((nl & 7) << 1) ^ ((b >> 3) & 3);
        *reinterpret_cast<half4*>(xs + slot * 4) = h;
    }
    __syncthreads();

    // ---- emit xh coalesced from LDS (half==0 blocks only) ----------------
    if (half == 0) {
        #pragma unroll
        for (int rep = 0; rep < NPB / 4; ++rep) {
            const int u = t + rep * 512;             // half4 id
            const int nl = u >> 7, b = (u >> 1) & 63, isl = u & 1;
            const int slot = (nl * 128 + b * 2 + isl) ^ ((nl & 7) << 1) ^ ((b >> 3) & 3);
            half4 h = *reinterpret_cast<const half4*>(xs + slot * 4);
            *reinterpret_cast<half4*>(xh + (size_t)n0 * 512 + u * 4) = h;
        }
    }

    const float* wb = W + (size_t)(cj >> 4) * 524288 + (size_t)n0 * 128 + (cj & 15) * 8 + hi * 4;
    ushort* whp = Wh + ((size_t)n0 * 512 + cj) * 8 + hi * 4;

    f32x16 acc0 = {}, acc1 = {};                     // b 0-31 / b 32-63
    float4 wv = *reinterpret_cast<const float4*>(wb);
    #pragma unroll 1
    for (int s = 0; s < NPB; ++s) {
        float4 wvn;
        if (s < NPB - 1)
            wvn = *reinterpret_cast<const float4*>(wb + (s + 1) * 128);
        const int sw = ((s & 7) << 1) ^ ((bl >> 3) & 3);
        const int slot0 = (s * 128 + bl * 2 + hi) ^ sw;
        const int slot1 = (s * 128 + bl * 2 + 64 + hi) ^ sw;
        half4 b0 = *reinterpret_cast<const half4*>(xs + slot0 * 4);
        half4 b1 = *reinterpret_cast<const half4*>(xs + slot1 * 4);
        half4 a;
        a[0] = (__fp16)wv.x; a[1] = (__fp16)wv.y; a[2] = (__fp16)wv.z; a[3] = (__fp16)wv.w;
        *reinterpret_cast<half4*>(whp + (size_t)s * 4096) = a;
        acc0 = __builtin_amdgcn_mfma_f32_32x32x8f16(a, b0, acc0, 0, 0, 0);
        acc1 = __builtin_amdgcn_mfma_f32_32x32x8f16(a, b1, acc1, 0, 0, 0);
        wv = wvn;
    }
    #pragma unroll
    for (int r = 0; r < 16; ++r) { acc0[r] *= 0.03125f; acc1[r] *= 0.03125f; }

    __syncthreads();                                 // xs dead -> sep may reuse
    // epilogue: sep[b 64][cjp_local 128], XOR-swizzled by b
    #pragma unroll
    for (int hb = 0; hb < 2; ++hb) {
        #pragma unroll
        for (int q = 0; q < 8; ++q) {
            const float e0 = hb ? acc1[2 * q] : acc0[2 * q];
            const float e1 = hb ? acc1[2 * q + 1] : acc0[2 * q + 1];
            U2 u; u.h = __builtin_amdgcn_cvt_pkrtz(e0, e1);
            const int cjp = w * 16 + 4 * (q >> 1) + (q & 1) + 2 * hi;  // local
            const int bb = bl + 32 * hb;
            sep[bb * 128 + (cjp ^ bb)] = u.u;
        }
    }
    __syncthreads();
    #pragma unroll
    for (int u2 = 0; u2 < 16; ++u2) {
        const int idx = t + u2 * 512;                // 0..8191
        const int ub = idx >> 7, ucjp = idx & 127;
        partial[(size_t)((ub >> 5) * NB + nblk) * 8192 + (ub & 31) * 256 + half * 128 + ucjp]
            = sep[ub * 128 + (ucjp ^ ub)];
    }
}

// ---- pass 1/2: softmax coupling; 2 n-steps per barrier; fp16 acc ----------

template <int NPB>
__global__ __launch_bounds__(512, 8) void pass12_kernel(
    const ushort* __restrict__ Wh,    // [N][CJ][I] fp16
    const ushort* __restrict__ xh,    // [N][B][I] fp16
    const ushort* __restrict__ OcumG, // [B][CJ] fp16
    unsigned* __restrict__ partial)   // [bid][bl 32][cjp 256] u32(h2)
{
    constexpr int NB = 4096 / NPB;
    const int bid = blockIdx.x;
    const int bt = bid / NB, nblk = bid % NB;
    const int n0 = nblk * NPB;
    const int t = threadIdx.x, l = t & 63, w = t >> 6;
    const int bl = l & 31, hi = l >> 5;
    const int b = bt * 32 + bl;

    // LDS union: pd (loop phase, 6KB) and sep (epilogue phase) share 32KB.
    __shared__ __align__(16) unsigned shbuf[8192];
    float* pd = reinterpret_cast<float*>(shbuf);     // [buf2][sub2][b32][w12]
    unsigned* sep = shbuf;

    const int cj0 = w * 64 + bl, cj1 = cj0 + 32;
    const ushort* xb = xh + ((size_t)n0 * 64 + b) * 8 + hi * 4;
    const ushort* whp0 = Wh + ((size_t)n0 * 512 + cj0) * 8 + hi * 4;
    const ushort* whp1 = Wh + ((size_t)n0 * 512 + cj1) * 8 + hi * 4;

    h2 oc[2][8];
    {
        const unsigned* og = reinterpret_cast<const unsigned*>(OcumG);
        #pragma unroll
        for (int mt = 0; mt < 2; ++mt) {
            const int cA = 4 * w + 2 * mt;
            const unsigned idx = (unsigned)b * 256 + cA * 8 + hi * 2;
            oc[mt][0] = uash2(og[idx]);      oc[mt][1] = uash2(og[idx + 1]);
            oc[mt][2] = uash2(og[idx + 4]);  oc[mt][3] = uash2(og[idx + 5]);
            oc[mt][4] = uash2(og[idx + 8]);  oc[mt][5] = uash2(og[idx + 9]);
            oc[mt][6] = uash2(og[idx + 12]); oc[mt][7] = uash2(og[idx + 13]);
        }
    }

    f32x16 zero = {};
    h2 acc0h[8], acc1h[8];
    #pragma unroll
    for (int q = 0; q < 8; ++q) {
        acc0h[q] = (h2)(__fp16)0.f;
        acc1h[q] = (h2)(__fp16)0.f;
    }

    half4 a0A = *reinterpret_cast<const half4*>(whp0);
    half4 a1A = *reinterpret_cast<const half4*>(whp1);
    half4 bfA = *reinterpret_cast<const half4*>(xb);
    half4 a0B = *reinterpret_cast<const half4*>(whp0 + 4096);
    half4 a1B = *reinterpret_cast<const half4*>(whp1 + 4096);
    half4 bfB = *reinterpret_cast<const half4*>(xb + 512);

    #pragma unroll 1
    for (int p = 0; p < NPB / 2; ++p) {
        half4 a0An, a1An, bfAn, a0Bn, a1Bn, bfBn;
        if (p < NPB / 2 - 1) {
            const int sA = 2 * p + 2, sB = 2 * p + 3;
            a0An = *reinterpret_cast<const half4*>(whp0 + (size_t)sA * 4096);
            a1An = *reinterpret_cast<const half4*>(whp1 + (size_t)sA * 4096);
            bfAn = *reinterpret_cast<const half4*>(xb + (size_t)sA * 512);
            a0Bn = *reinterpret_cast<const half4*>(whp0 + (size_t)sB * 4096);
            a1Bn = *reinterpret_cast<const half4*>(whp1 + (size_t)sB * 4096);
            bfBn = *reinterpret_cast<const half4*>(xb + (size_t)sB * 512);
        }
        h2 hA0[8], hA1[8];
        {
            f32x16 d0 = __builtin_amdgcn_mfma_f32_32x32x8f16(a0A, bfA, zero, 0, 0, 0);
            f32x16 d1 = __builtin_amdgcn_mfma_f32_32x32x8f16(a1A, bfA, zero, 0, 0, 0);
            #pragma unroll
            for (int q = 0; q < 8; ++q) {
                hA0[q] = __builtin_amdgcn_cvt_pkrtz(d0[2 * q], d0[2 * q + 1]);
                hA1[q] = __builtin_amdgcn_cvt_pkrtz(d1[2 * q], d1[2 * q + 1]);
            }
        }
        float pA0_A = fdot2(hA0[3], oc[0][3], fdot2(hA0[2], oc[0][2], fdot2(hA0[1], oc[0][1], fdot2(hA0[0], oc[0][0], 0.f))));
        float pB0_A = fdot2(hA0[7], oc[0][7], fdot2(hA0[6], oc[0][6], fdot2(hA0[5], oc[0][5], fdot2(hA0[4], oc[0][4], 0.f))));
        float pA1_A = fdot2(hA1[3], oc[1][3], fdot2(hA1[2], oc[1][2], fdot2(hA1[1], oc[1][1], fdot2(hA1[0], oc[1][0], 0.f))));
        float pB1_A = fdot2(hA1[7], oc[1][7], fdot2(hA1[6], oc[1][6], fdot2(hA1[5], oc[1][5], fdot2(hA1[4], oc[1][4], 0.f))));
        h2 hB0[8], hB1[8];
        {
            f32x16 d0 = __builtin_amdgcn_mfma_f32_32x32x8f16(a0B, bfB, zero, 0, 0, 0);
            f32x16 d1 = __builtin_amdgcn_mfma_f32_32x32x8f16(a1B, bfB, zero, 0, 0, 0);
            #pragma unroll
            for (int q = 0; q < 8; ++q) {
                hB0[q] = __builtin_amdgcn_cvt_pkrtz(d0[2 * q], d0[2 * q + 1]);
                hB1[q] = __builtin_amdgcn_cvt_pkrtz(d1[2 * q], d1[2 * q + 1]);
            }
        }
        float pA0_B = fdot2(hB0[3], oc[0][3], fdot2(hB0[2], oc[0][2], fdot2(hB0[1], oc[0][1], fdot2(hB0[0], oc[0][0], 0.f))));
        float pB0_B = fdot2(hB0[7], oc[0][7], fdot2(hB0[6], oc[0][6], fdot2(hB0[5], oc[0][5], fdot2(hB0[4], oc[0][4], 0.f))));
        float pA1_B = fdot2(hB1[3], oc[1][3], fdot2(hB1[2], oc[1][2], fdot2(hB1[1], oc[1][1], fdot2(hB1[0], oc[1][0], 0.f))));
        float pB1_B = fdot2(hB1[7], oc[1][7], fdot2(hB1[6], oc[1][6], fdot2(hB1[5], oc[1][5], fdot2(hB1[4], oc[1][4], 0.f))));

        pA0_A += __shfl_xor(pA0_A, 32, 64);
        pB0_A += __shfl_xor(pB0_A, 32, 64);
        pA1_A += __shfl_xor(pA1_A, 32, 64);
        pB1_A += __shfl_xor(pB1_A, 32, 64);
        pA0_B += __shfl_xor(pA0_B, 32, 64);
        pB0_B += __shfl_xor(pB0_B, 32, 64);
        pA1_B += __shfl_xor(pA1_B, 32, 64);
        pB1_B += __shfl_xor(pB1_B, 32, 64);

        float eA0_A = __expf(pA0_A), eB0_A = __expf(pB0_A);
        float eA1_A = __expf(pA1_A), eB1_A = __expf(pB1_A);
        float eA0_B = __expf(pA0_B), eB0_B = __expf(pB0_B);
        float eA1_B = __expf(pA1_B), eB1_B = __expf(pB1_B);

        const int buf = p & 1;
        if (l < 32) {
            pd[((buf * 2 + 0) * 32 + bl) * 12 + w] = eA0_A + eB0_A + eA1_A + eB1_A;
            pd[((buf * 2 + 1) * 32 + bl) * 12 + w] = eA0_B + eB0_B + eA1_B + eB1_B;
        }
        __syncthreads();
        const float4 qa0 = *reinterpret_cast<const float4*>(&pd[((buf * 2 + 0) * 32 + bl) * 12 + 0]);
        const float4 qa1 = *reinterpret_cast<const float4*>(&pd[((buf * 2 + 0) * 32 + bl) * 12 + 4]);
        const float4 qb0 = *reinterpret_cast<const float4*>(&pd[((buf * 2 + 1) * 32 + bl) * 12 + 0]);
        const float4 qb1 = *reinterpret_cast<const float4*>(&pd[((buf * 2 + 1) * 32 + bl) * 12 + 4]);
        const float rdA = __builtin_amdgcn_rcpf(qa0.x + qa0.y + qa0.z + qa0.w +
                                                qa1.x + qa1.y + qa1.z + qa1.w);
        const float rdB = __builtin_amdgcn_rcpf(qb0.x + qb0.y + qb0.z + qb0.w +
                                                qb1.x + qb1.y + qb1.z + qb1.w);

        h2 c0A, c1A, c0B, c1B, c2A, c3A, c2B, c3B;
        c0A.x = (__fp16)(eA0_A * rdA); c0A.y = c0A.x;
        c1A.x = (__fp16)(eB0_A * rdA); c1A.y = c1A.x;
        c2A.x = (__fp16)(eA1_A * rdA); c2A.y = c2A.x;
        c3A.x = (__fp16)(eB1_A * rdA); c3A.y = c3A.x;
        c0B.x = (__fp16)(eA0_B * rdB); c0B.y = c0B.x;
        c1B.x = (__fp16)(eB0_B * rdB); c1B.y = c1B.x;
        c2B.x = (__fp16)(eA1_B * rdB); c2B.y = c2B.x;
        c3B.x = (__fp16)(eB1_B * rdB); c3B.y = c3B.x;

        #pragma unroll
        for (int q = 0; q < 4; ++q) {
            acc0h[q] = hA0[q] * c0A + acc0h[q];
            acc0h[q + 4] = hA0[q + 4] * c1A + acc0h[q + 4];
            acc1h[q] = hA1[q] * c2A + acc1h[q];
            acc1h[q + 4] = hA1[q + 4] * c3A + acc1h[q + 4];
        }
        #pragma unroll
        for (int q = 0; q < 4; ++q) {
            acc0h[q] = hB0[q] * c0B + acc0h[q];
            acc0h[q + 4] = hB0[q + 4] * c1B + acc0h[q + 4];
            acc1h[q] = hB1[q] * c2B + acc1h[q];
            acc1h[q + 4] = hB1[q + 4] * c3B + acc1h[q + 4];
        }
        a0A = a0An; a1A = a1An; bfA = bfAn;
        a0B = a0Bn; a1B = a1Bn; bfB = bfBn;
    }

    __syncthreads();                                 // pd dead -> sep may reuse
    #pragma unroll
    for (int mt = 0; mt < 2; ++mt) {
        #pragma unroll
        for (int q = 0; q < 8; ++q) {
            U2 u; u.h = mt ? acc1h[q] : acc0h[q];
            const int cjp = w * 32 + mt * 16 + 4 * (q >> 1) + (q & 1) + 2 * hi;
            sep[bl * 256 + (cjp ^ bl)] = u.u;
        }
    }
    __syncthreads();
    const unsigned gbase = (unsigned)bid * 8192;
    #pragma unroll
    for (int u2 = 0; u2 < 16; ++u2) {
        const int idx = t + u2 * 512;
        const int ubl = idx >> 8, ucjp = idx & 255;
        partial[gbase + idx] = sep[ubl * 256 + (ucjp ^ ubl)];
    }
}

// ---- final reduce + squash + Ocum update (SUB threads per output) ---------

template <int NB, int SUB>
__global__ __launch_bounds__(256) void reduce_squash(const unsigned* __restrict__ partial32,
                                                     ushort* __restrict__ OcumG,
                                                     float* __restrict__ out,
                                                     int passIdx) {
    const int gtid = blockIdx.x * 256 + threadIdx.x;  // 0..16384*SUB-1
    const int oid = gtid / SUB, sub = gtid % SUB;
    const int b = oid >> 8, cjp = oid & 255;
    const int bt = b >> 5, bl = b & 31;
    const unsigned base = (unsigned)bt * (unsigned)NB * 8192u + (unsigned)bl * 256u + (unsigned)cjp;
    float sx = 0.f, sy = 0.f;
    #pragma unroll 8
    for (int i = 0; i < NB / SUB; ++i) {
        U2 v; v.u = partial32[base + (unsigned)(sub + SUB * i) * 8192u];
        sx += (float)v.h.x;
        sy += (float)v.h.y;
    }
    sx += __shfl_xor(sx, 1, 64); sy += __shfl_xor(sy, 1, 64);
    sx += __shfl_xor(sx, 2, 64); sy += __shfl_xor(sy, 2, 64);
    if constexpr (SUB == 8) { sx += __shfl_xor(sx, 4, 64); sy += __shfl_xor(sy, 4, 64); }
    float s2 = sx * sx + sy * sy;                    // sum over capsule's 8 cjp
    s2 += __shfl_xor(s2, SUB, 64);
    s2 += __shfl_xor(s2, 2 * SUB, 64);
    s2 += __shfl_xor(s2, 4 * SUB, 64);
    float scale = (s2 / (1.f + s2)) / sqrtf(s2 + 1e-7f);
    float o0 = scale * sx, o1 = scale * sy;

    if (sub == 0) {
        unsigned* ocp = reinterpret_cast<unsigned*>(OcumG) + b * 256 + cjp;
        float a0 = o0, a1 = o1;
        if (passIdx) {
            U2 old; old.u = *ocp;
            a0 += (float)old.h.x;
            a1 += (float)old.h.y;
        }
        U2 nw; nw.h = __builtin_amdgcn_cvt_pkrtz(a0, a1);
        *ocp = nw.u;
        if (passIdx == 2) {
            out[b * 512 + cjp * 2] = o0;
            out[b * 512 + cjp * 2 + 1] = o1;
        }
    }
}

// ---- host ------------------------------------------------------------------

extern "C" void kernel_launch(void* const* d_in, const int* in_sizes, int n_in,
                              void* d_out, int out_size, void* d_ws, size_t ws_size,
                              hipStream_t stream) {
    const float* x = (const float*)d_in[0];
    const float* W = (const float*)d_in[1];
    float* out = (float*)d_out;

    char* ws = (char*)d_ws;
    ushort* Wh = (ushort*)ws;                                        // 32 MiB
    const size_t MiB = 1024 * 1024;

    if (ws_size >= 68 * MiB + 65536) {
        // NPB=8: partial 32 MiB | xh 4 MiB | Ocum 64 KiB
        unsigned* partialU = (unsigned*)(ws + 32 * MiB);
        ushort* xh = (ushort*)(ws + 64 * MiB);
        ushort* OcumG = (ushort*)(ws + 68 * MiB);
        pass0_kernel<8><<<1024, 512, 0, stream>>>(W, x, Wh, xh, partialU);
        reduce_squash<512, 8><<<512, 256, 0, stream>>>(partialU, OcumG, out, 0);
        pass12_kernel<8><<<1024, 512, 0, stream>>>(Wh, xh, OcumG, partialU);
        reduce_squash<512, 8><<<512, 256, 0, stream>>>(partialU, OcumG, out, 1);
        pass12_kernel<8><<<1024, 512, 0, stream>>>(Wh, xh, OcumG, partialU);
        reduce_squash<512, 8><<<512, 256, 0, stream>>>(partialU, OcumG, out, 2);
    } else {
        // fallback NPB=16 (round-14 layout): partial 16 | xh 4 | Ocum 64 KiB
        unsigned* partialU = (unsigned*)(ws + 32 * MiB);
        ushort* xh = (ushort*)(ws + 48 * MiB);
        ushort* OcumG = (ushort*)(ws + 52 * MiB);
        pass0_kernel<16><<<512, 512, 0, stream>>>(W, x, Wh, xh, partialU);
        reduce_squash<256, 4><<<256, 256, 0, stream>>>(partialU, OcumG, out, 0);
        pass12_kernel<16><<<512, 512, 0, stream>>>(Wh, xh, OcumG, partialU);
        reduce_squash<256, 4><<<256, 256, 0, stream>>>(partialU, OcumG, out, 1);
        pass12_kernel<16><<<512, 512, 0, stream>>>(Wh, xh, OcumG, partialU);
        reduce_squash<256, 4><<<256, 256, 0, stream>>>(partialU, OcumG, out, 2);
    }
}

// Round 10
// 166.893 us; speedup vs baseline: 3.0922x; 2.1016x over previous
//
#include <hip/hip_runtime.h>
#include <math.h>

// CapsuleLayer dynamic routing — round 17: n-paired 16B load layout.
// B=64, N=4096, I=8, C=32, D=16, 3 routing iterations.
//
// Round-16 post-mortem: NPB=8 + 4 blocks/CU REGRESSED (350us): occupancy 74%
// but pass12 3x slower with 205MB fetch -> small tiles thrash L2/L3, and the
// (512,8) VGPR-32 squeeze killed prefetch. Occupancy was never the lever;
// pass12 is per-wave memory-latency bound on SIX 8B loads per 2n iteration.
// Round 17 = round-14 base (167.6us verified) + ONE change: pair the n-dim
// into the load word. Wh[np][cj][hi][par][i4] and xh[np][b][hi][par][i4]
// so one 16B dwordx4 per stream delivers BOTH sub-steps' fragments:
// 6 loads -> 3 per iteration, each a 1KB/wave coalesced transaction.
// All math (MFMA map, softmax, fp16 acc, swizzles, squash) verbatim r14.
//
// ws (NPB=16): Wh fp16 32 MiB | partial u32(h2) 16 MiB | xh fp16 4 MiB |
//              OcumG fp16 64 KiB (52.07)

typedef __fp16 h2 __attribute__((ext_vector_type(2)));
typedef __fp16 half4 __attribute__((ext_vector_type(4)));
typedef float f32x16 __attribute__((ext_vector_type(16)));

union U2 { h2 h; unsigned u; };

__device__ __forceinline__ float fdot2(h2 a, h2 b, float c) {
    return __builtin_amdgcn_fdot2(a, b, c, false);
}
__device__ __forceinline__ h2 uash2(unsigned u) { U2 t; t.u = u; return t.h; }

// ---- pass 0: uniform coupling; cj-split; LDS-staged x; emits Wh and xh ----

template <int NPB>
__global__ __launch_bounds__(512, 4) void pass0_kernel(
    const float* __restrict__ W,      // [C][N][D][I] f32
    const float* __restrict__ x,      // [B][N][I] f32
    ushort* __restrict__ Wh,          // [np][cj][hi][par][i4] fp16
    ushort* __restrict__ xh,          // [np][b][hi][par][i4] fp16
    unsigned* __restrict__ partial)   // [(bt*NB+nblk)][bl 32][cjp 256] u32(h2)
{
    constexpr int NB = 4096 / NPB;
    const int bid = blockIdx.x;
    const int half = bid / NB, nblk = bid % NB;      // XCD = bid%8 = nblk%8
    const int n0 = nblk * NPB;
    const int t = threadIdx.x, l = t & 63, w = t >> 6;
    const int bl = l & 31, hi = l >> 5;
    const int cj = half * 256 + w * 32 + bl;         // this lane's A-row

    __shared__ __align__(16) ushort xs[NPB * 512];   // [n][b][i] fp16, swizzled
    __shared__ unsigned sep[8192];                   // 32KB epilogue staging

    // ---- stage x tile: coalesced f32 read -> fp16 -> swizzled LDS --------
    #pragma unroll
    for (int rep = 0; rep < NPB / 4; ++rep) {
        const int idx = t + rep * 512;               // float4 id, 0..NPB*128-1
        const int b = idx / (2 * NPB), f4 = idx % (2 * NPB);
        const int nl = f4 >> 1, isl = f4 & 1;
        float4 v = *reinterpret_cast<const float4*>(
            x + (size_t)b * 32768 + (size_t)n0 * 8 + f4 * 4);
        half4 h;
        h[0] = (__fp16)v.x; h[1] = (__fp16)v.y; h[2] = (__fp16)v.z; h[3] = (__fp16)v.w;
        const int slot = (nl * 128 + b * 2 + isl) ^ ((nl & 7) << 1) ^ ((b >> 3) & 3);
        *reinterpret_cast<half4*>(xs + slot * 4) = h;
    }
    __syncthreads();

    // ---- emit xh (paired layout) from LDS (half==0 blocks only) ----------
    if (half == 0) {
        #pragma unroll
        for (int rep = 0; rep < NPB / 4; ++rep) {
            const int u = t + rep * 512;             // half4 id = (nl, b, isl)
            const int nl = u >> 7, b = (u >> 1) & 63, isl = u & 1;
            const int slot = (nl * 128 + b * 2 + isl) ^ ((nl & 7) << 1) ^ ((b >> 3) & 3);
            half4 h = *reinterpret_cast<const half4*>(xs + slot * 4);
            // xh[np][b][isl(=hi)][par][i4]
            const size_t dst = (((size_t)((n0 >> 1) + (nl >> 1)) * 64 + b) * 2 + isl) * 8
                               + (nl & 1) * 4;
            *reinterpret_cast<half4*>(xh + dst) = h;
        }
    }

    const float* wb = W + (size_t)(cj >> 4) * 524288 + (size_t)n0 * 128 + (cj & 15) * 8 + hi * 4;
    ushort* whp = Wh + ((size_t)(n0 >> 1) * 512 + cj) * 16 + hi * 8;  // paired

    f32x16 acc0 = {}, acc1 = {};                     // b 0-31 / b 32-63
    float4 wv = *reinterpret_cast<const float4*>(wb);
    #pragma unroll 1
    for (int s = 0; s < NPB; ++s) {
        float4 wvn;
        if (s < NPB - 1)
            wvn = *reinterpret_cast<const float4*>(wb + (s + 1) * 128);
        const int sw = ((s & 7) << 1) ^ ((bl >> 3) & 3);
        const int slot0 = (s * 128 + bl * 2 + hi) ^ sw;
        const int slot1 = (s * 128 + bl * 2 + 64 + hi) ^ sw;
        half4 b0 = *reinterpret_cast<const half4*>(xs + slot0 * 4);
        half4 b1 = *reinterpret_cast<const half4*>(xs + slot1 * 4);
        half4 a;
        a[0] = (__fp16)wv.x; a[1] = (__fp16)wv.y; a[2] = (__fp16)wv.z; a[3] = (__fp16)wv.w;
        *reinterpret_cast<half4*>(whp + (size_t)(s >> 1) * 8192 + (s & 1) * 4) = a;
        acc0 = __builtin_amdgcn_mfma_f32_32x32x8f16(a, b0, acc0, 0, 0, 0);
        acc1 = __builtin_amdgcn_mfma_f32_32x32x8f16(a, b1, acc1, 0, 0, 0);
        wv = wvn;
    }
    #pragma unroll
    for (int r = 0; r < 16; ++r) { acc0[r] *= 0.03125f; acc1[r] *= 0.03125f; }

    // epilogue: sep[b 64][cjp_local 128], XOR-swizzled by b
    #pragma unroll
    for (int hb = 0; hb < 2; ++hb) {
        #pragma unroll
        for (int q = 0; q < 8; ++q) {
            const float e0 = hb ? acc1[2 * q] : acc0[2 * q];
            const float e1 = hb ? acc1[2 * q + 1] : acc0[2 * q + 1];
            U2 u; u.h = __builtin_amdgcn_cvt_pkrtz(e0, e1);
            const int cjp = w * 16 + 4 * (q >> 1) + (q & 1) + 2 * hi;  // local
            const int bb = bl + 32 * hb;
            sep[bb * 128 + (cjp ^ bb)] = u.u;
        }
    }
    __syncthreads();
    #pragma unroll
    for (int u2 = 0; u2 < 16; ++u2) {
        const int idx = t + u2 * 512;                // 0..8191
        const int ub = idx >> 7, ucjp = idx & 127;
        partial[(size_t)((ub >> 5) * NB + nblk) * 8192 + (ub & 31) * 256 + half * 128 + ucjp]
            = sep[ub * 128 + (ucjp ^ ub)];
    }
}

// ---- pass 1/2: softmax coupling; 2 n-steps per barrier; fp16 acc ----------

template <int NPB>
__global__ __launch_bounds__(512, 4) void pass12_kernel(
    const ushort* __restrict__ Wh,    // [np][cj][hi][par][i4] fp16
    const ushort* __restrict__ xh,    // [np][b][hi][par][i4] fp16
    const ushort* __restrict__ OcumG, // [B][CJ] fp16
    unsigned* __restrict__ partial)   // [bid][bl 32][cjp 256] u32(h2)
{
    constexpr int NB = 4096 / NPB;
    const int bid = blockIdx.x;
    const int bt = bid / NB, nblk = bid % NB;
    const int n0 = nblk * NPB;
    const int t = threadIdx.x, l = t & 63, w = t >> 6;
    const int bl = l & 31, hi = l >> 5;
    const int b = bt * 32 + bl;

    __shared__ __align__(16) float pd[2][2][32][12]; // [buf][sub][b][wave]
    __shared__ unsigned sep[8192];                   // 32KB epilogue staging

    const int cj0 = w * 64 + bl, cj1 = cj0 + 32;
    const ushort* xb = xh + (((size_t)(n0 >> 1) * 64 + b) * 2 + hi) * 8;
    const ushort* whp0 = Wh + ((size_t)(n0 >> 1) * 512 + cj0) * 16 + hi * 8;
    const ushort* whp1 = Wh + ((size_t)(n0 >> 1) * 512 + cj1) * 16 + hi * 8;

    h2 oc[2][8];
    {
        const unsigned* og = reinterpret_cast<const unsigned*>(OcumG);
        #pragma unroll
        for (int mt = 0; mt < 2; ++mt) {
            const int cA = 4 * w + 2 * mt;
            const unsigned idx = (unsigned)b * 256 + cA * 8 + hi * 2;
            oc[mt][0] = uash2(og[idx]);      oc[mt][1] = uash2(og[idx + 1]);
            oc[mt][2] = uash2(og[idx + 4]);  oc[mt][3] = uash2(og[idx + 5]);
            oc[mt][4] = uash2(og[idx + 8]);  oc[mt][5] = uash2(og[idx + 9]);
            oc[mt][6] = uash2(og[idx + 12]); oc[mt][7] = uash2(og[idx + 13]);
        }
    }

    f32x16 zero = {};
    h2 acc0h[8], acc1h[8];                           // fp16 accumulators
    #pragma unroll
    for (int q = 0; q < 8; ++q) {
        acc0h[q] = (h2)(__fp16)0.f;
        acc1h[q] = (h2)(__fp16)0.f;
    }

    uint4 w0 = *reinterpret_cast<const uint4*>(whp0);
    uint4 w1 = *reinterpret_cast<const uint4*>(whp1);
    uint4 xv = *reinterpret_cast<const uint4*>(xb);

    #pragma unroll 1
    for (int p = 0; p < NPB / 2; ++p) {
        uint4 w0n, w1n, xvn;
        if (p < NPB / 2 - 1) {
            w0n = *reinterpret_cast<const uint4*>(whp0 + (size_t)(p + 1) * 8192);
            w1n = *reinterpret_cast<const uint4*>(whp1 + (size_t)(p + 1) * 8192);
            xvn = *reinterpret_cast<const uint4*>(xb + (size_t)(p + 1) * 1024);
        }
        const half4* w0h = reinterpret_cast<const half4*>(&w0);
        const half4* w1h = reinterpret_cast<const half4*>(&w1);
        const half4* xvh = reinterpret_cast<const half4*>(&xv);
        const half4 a0A = w0h[0], a0B = w0h[1];
        const half4 a1A = w1h[0], a1B = w1h[1];
        const half4 bfA = xvh[0], bfB = xvh[1];

        // ---- sub-step A -----------------------------------------------
        h2 hA0[8], hA1[8];
        {
            f32x16 d0 = __builtin_amdgcn_mfma_f32_32x32x8f16(a0A, bfA, zero, 0, 0, 0);
            f32x16 d1 = __builtin_amdgcn_mfma_f32_32x32x8f16(a1A, bfA, zero, 0, 0, 0);
            #pragma unroll
            for (int q = 0; q < 8; ++q) {
                hA0[q] = __builtin_amdgcn_cvt_pkrtz(d0[2 * q], d0[2 * q + 1]);
                hA1[q] = __builtin_amdgcn_cvt_pkrtz(d1[2 * q], d1[2 * q + 1]);
            }
        }
        float pA0_A = fdot2(hA0[3], oc[0][3], fdot2(hA0[2], oc[0][2], fdot2(hA0[1], oc[0][1], fdot2(hA0[0], oc[0][0], 0.f))));
        float pB0_A = fdot2(hA0[7], oc[0][7], fdot2(hA0[6], oc[0][6], fdot2(hA0[5], oc[0][5], fdot2(hA0[4], oc[0][4], 0.f))));
        float pA1_A = fdot2(hA1[3], oc[1][3], fdot2(hA1[2], oc[1][2], fdot2(hA1[1], oc[1][1], fdot2(hA1[0], oc[1][0], 0.f))));
        float pB1_A = fdot2(hA1[7], oc[1][7], fdot2(hA1[6], oc[1][6], fdot2(hA1[5], oc[1][5], fdot2(hA1[4], oc[1][4], 0.f))));
        // ---- sub-step B -----------------------------------------------
        h2 hB0[8], hB1[8];
        {
            f32x16 d0 = __builtin_amdgcn_mfma_f32_32x32x8f16(a0B, bfB, zero, 0, 0, 0);
            f32x16 d1 = __builtin_amdgcn_mfma_f32_32x32x8f16(a1B, bfB, zero, 0, 0, 0);
            #pragma unroll
            for (int q = 0; q < 8; ++q) {
                hB0[q] = __builtin_amdgcn_cvt_pkrtz(d0[2 * q], d0[2 * q + 1]);
                hB1[q] = __builtin_amdgcn_cvt_pkrtz(d1[2 * q], d1[2 * q + 1]);
            }
        }
        float pA0_B = fdot2(hB0[3], oc[0][3], fdot2(hB0[2], oc[0][2], fdot2(hB0[1], oc[0][1], fdot2(hB0[0], oc[0][0], 0.f))));
        float pB0_B = fdot2(hB0[7], oc[0][7], fdot2(hB0[6], oc[0][6], fdot2(hB0[5], oc[0][5], fdot2(hB0[4], oc[0][4], 0.f))));
        float pA1_B = fdot2(hB1[3], oc[1][3], fdot2(hB1[2], oc[1][2], fdot2(hB1[1], oc[1][1], fdot2(hB1[0], oc[1][0], 0.f))));
        float pB1_B = fdot2(hB1[7], oc[1][7], fdot2(hB1[6], oc[1][6], fdot2(hB1[5], oc[1][5], fdot2(hB1[4], oc[1][4], 0.f))));

        pA0_A += __shfl_xor(pA0_A, 32, 64);
        pB0_A += __shfl_xor(pB0_A, 32, 64);
        pA1_A += __shfl_xor(pA1_A, 32, 64);
        pB1_A += __shfl_xor(pB1_A, 32, 64);
        pA0_B += __shfl_xor(pA0_B, 32, 64);
        pB0_B += __shfl_xor(pB0_B, 32, 64);
        pA1_B += __shfl_xor(pA1_B, 32, 64);
        pB1_B += __shfl_xor(pB1_B, 32, 64);

        float eA0_A = __expf(pA0_A), eB0_A = __expf(pB0_A);
        float eA1_A = __expf(pA1_A), eB1_A = __expf(pB1_A);
        float eA0_B = __expf(pA0_B), eB0_B = __expf(pB0_B);
        float eA1_B = __expf(pA1_B), eB1_B = __expf(pB1_B);

        const int buf = p & 1;
        if (l < 32) {
            pd[buf][0][bl][w] = eA0_A + eB0_A + eA1_A + eB1_A;
            pd[buf][1][bl][w] = eA0_B + eB0_B + eA1_B + eB1_B;
        }
        __syncthreads();
        const float4 qa0 = *reinterpret_cast<const float4*>(&pd[buf][0][bl][0]);
        const float4 qa1 = *reinterpret_cast<const float4*>(&pd[buf][0][bl][4]);
        const float4 qb0 = *reinterpret_cast<const float4*>(&pd[buf][1][bl][0]);
        const float4 qb1 = *reinterpret_cast<const float4*>(&pd[buf][1][bl][4]);
        const float rdA = __builtin_amdgcn_rcpf(qa0.x + qa0.y + qa0.z + qa0.w +
                                                qa1.x + qa1.y + qa1.z + qa1.w);
        const float rdB = __builtin_amdgcn_rcpf(qb0.x + qb0.y + qb0.z + qb0.w +
                                                qb1.x + qb1.y + qb1.z + qb1.w);

        h2 c0A, c1A, c0B, c1B, c2A, c3A, c2B, c3B;
        c0A.x = (__fp16)(eA0_A * rdA); c0A.y = c0A.x;  // acc0 rows<8  (c=4w)
        c1A.x = (__fp16)(eB0_A * rdA); c1A.y = c1A.x;  // acc0 rows>=8 (c=4w+1)
        c2A.x = (__fp16)(eA1_A * rdA); c2A.y = c2A.x;  // acc1 rows<8  (c=4w+2)
        c3A.x = (__fp16)(eB1_A * rdA); c3A.y = c3A.x;  // acc1 rows>=8 (c=4w+3)
        c0B.x = (__fp16)(eA0_B * rdB); c0B.y = c0B.x;
        c1B.x = (__fp16)(eB0_B * rdB); c1B.y = c1B.x;
        c2B.x = (__fp16)(eA1_B * rdB); c2B.y = c2B.x;
        c3B.x = (__fp16)(eB1_B * rdB); c3B.y = c3B.x;

        #pragma unroll
        for (int q = 0; q < 4; ++q) {
            acc0h[q] = hA0[q] * c0A + acc0h[q];
            acc0h[q + 4] = hA0[q + 4] * c1A + acc0h[q + 4];
            acc1h[q] = hA1[q] * c2A + acc1h[q];
            acc1h[q + 4] = hA1[q + 4] * c3A + acc1h[q + 4];
        }
        #pragma unroll
        for (int q = 0; q < 4; ++q) {
            acc0h[q] = hB0[q] * c0B + acc0h[q];
            acc0h[q + 4] = hB0[q + 4] * c1B + acc0h[q + 4];
            acc1h[q] = hB1[q] * c2B + acc1h[q];
            acc1h[q + 4] = hB1[q + 4] * c3B + acc1h[q + 4];
        }
        w0 = w0n; w1 = w1n; xv = xvn;
    }

    // ---- epilogue: stage h2 partial tile in LDS (XOR-swizzled), copy out --
    __syncthreads();
    #pragma unroll
    for (int mt = 0; mt < 2; ++mt) {
        #pragma unroll
        for (int q = 0; q < 8; ++q) {
            U2 u; u.h = mt ? acc1h[q] : acc0h[q];
            const int cjp = w * 32 + mt * 16 + 4 * (q >> 1) + (q & 1) + 2 * hi;
            sep[bl * 256 + (cjp ^ bl)] = u.u;   // swizzle: conflict-free banks
        }
    }
    __syncthreads();
    const unsigned gbase = (unsigned)bid * 8192;
    #pragma unroll
    for (int u2 = 0; u2 < 16; ++u2) {
        const int idx = t + u2 * 512;
        const int ubl = idx >> 8, ucjp = idx & 255;
        partial[gbase + idx] = sep[ubl * 256 + (ucjp ^ ubl)];
    }
}

// ---- final reduce + squash + Ocum update (4 threads per output) -----------

template <int NB>
__global__ __launch_bounds__(256) void reduce_squash(const unsigned* __restrict__ partial32,
                                                     ushort* __restrict__ OcumG,
                                                     float* __restrict__ out,
                                                     int passIdx) {
    const int gtid = blockIdx.x * 256 + threadIdx.x;  // 0..65535
    const int oid = gtid >> 2, sub = gtid & 3;
    const int b = oid >> 8, cjp = oid & 255;
    const int bt = b >> 5, bl = b & 31;
    const unsigned base = (unsigned)bt * (unsigned)NB * 8192u + (unsigned)bl * 256u + (unsigned)cjp;
    float sx = 0.f, sy = 0.f;
    #pragma unroll 8
    for (int i = 0; i < NB / 4; ++i) {
        U2 v; v.u = partial32[base + (unsigned)(sub + 4 * i) * 8192u];
        sx += (float)v.h.x;
        sy += (float)v.h.y;
    }
    sx += __shfl_xor(sx, 1, 64); sy += __shfl_xor(sy, 1, 64);
    sx += __shfl_xor(sx, 2, 64); sy += __shfl_xor(sy, 2, 64);
    float s2 = sx * sx + sy * sy;                    // sum over capsule's 8 cjp
    s2 += __shfl_xor(s2, 4, 64);
    s2 += __shfl_xor(s2, 8, 64);
    s2 += __shfl_xor(s2, 16, 64);
    float scale = (s2 / (1.f + s2)) / sqrtf(s2 + 1e-7f);
    float o0 = scale * sx, o1 = scale * sy;

    if (sub == 0) {
        unsigned* ocp = reinterpret_cast<unsigned*>(OcumG) + b * 256 + cjp;
        float a0 = o0, a1 = o1;
        if (passIdx) {
            U2 old; old.u = *ocp;
            a0 += (float)old.h.x;
            a1 += (float)old.h.y;
        }
        U2 nw; nw.h = __builtin_amdgcn_cvt_pkrtz(a0, a1);
        *ocp = nw.u;
        if (passIdx == 2) {
            out[b * 512 + cjp * 2] = o0;
            out[b * 512 + cjp * 2 + 1] = o1;
        }
    }
}

// ---- host ------------------------------------------------------------------

extern "C" void kernel_launch(void* const* d_in, const int* in_sizes, int n_in,
                              void* d_out, int out_size, void* d_ws, size_t ws_size,
                              hipStream_t stream) {
    const float* x = (const float*)d_in[0];
    const float* W = (const float*)d_in[1];
    float* out = (float*)d_out;

    char* ws = (char*)d_ws;
    ushort* Wh = (ushort*)ws;                                        // 32 MiB
    const size_t MiB = 1024 * 1024;

    if (ws_size >= 52 * MiB + 65536) {
        // NPB=16: partial 16 MiB | xh 4 MiB | Ocum 64 KiB
        unsigned* partialU = (unsigned*)(ws + 32 * MiB);
        ushort* xh = (ushort*)(ws + 48 * MiB);
        ushort* OcumG = (ushort*)(ws + 52 * MiB);
        pass0_kernel<16><<<512, 512, 0, stream>>>(W, x, Wh, xh, partialU);
        reduce_squash<256><<<256, 256, 0, stream>>>(partialU, OcumG, out, 0);
        pass12_kernel<16><<<512, 512, 0, stream>>>(Wh, xh, OcumG, partialU);
        reduce_squash<256><<<256, 256, 0, stream>>>(partialU, OcumG, out, 1);
        pass12_kernel<16><<<512, 512, 0, stream>>>(Wh, xh, OcumG, partialU);
        reduce_squash<256><<<256, 256, 0, stream>>>(partialU, OcumG, out, 2);
    } else {
        // fallback NPB=32: partial 8 MiB | xh 4 MiB | Ocum 64 KiB (44.07 MiB)
        unsigned* partialU = (unsigned*)(ws + 32 * MiB);
        ushort* xh = (ushort*)(ws + 40 * MiB);
        ushort* OcumG = (ushort*)(ws + 44 * MiB);
        pass0_kernel<32><<<256, 512, 0, stream>>>(W, x, Wh, xh, partialU);
        reduce_squash<128><<<256, 256, 0, stream>>>(partialU, OcumG, out, 0);
        pass12_kernel<32><<<256, 512, 0, stream>>>(Wh, xh, OcumG, partialU);
        reduce_squash<128><<<256, 256, 0, stream>>>(partialU, OcumG, out, 1);
        pass12_kernel<32><<<256, 512, 0, stream>>>(Wh, xh, OcumG, partialU);
        reduce_squash<128><<<256, 256, 0, stream>>>(partialU, OcumG, out, 2);
    }
}